// Round 1
// baseline (164.595 us; speedup 1.0000x reference)
//
#include <hip/hip_runtime.h>

// Problem constants (match reference)
#define BATCH 32
#define NBOX 1024
#define NCLS 15
#define MAXM 300
#define CONF_THR 0.1f
#define KEEP_THR 0.2f
#define FEPS 1e-7f

// ---------------------------------------------------------------------------
// ProbIoU between box i (1) and box j (2), following the reference op order
// exactly, with FP contraction disabled to match numpy float32 semantics.
// ---------------------------------------------------------------------------
__device__ __forceinline__ float probiou(
    float x1, float y1, float a1, float b1, float c1, float det1,
    float x2, float y2, float a2, float b2, float c2, float det2) {
#pragma clang fp contract(off)
  float dx = x1 - x2;
  float dy = y1 - y2;
  float sa = a1 + a2;
  float sb = b1 + b2;
  float sc = c1 + c2;
  float denom = sa * sb - sc * sc + FEPS;
  float t1 = (sa * dy * dy + sb * dx * dx) / denom * 0.25f;
  float t2 = (sc * (-dx) * dy) / denom * 0.5f;
  float t3 = 0.5f * logf(denom / (4.0f * sqrtf(det1 * det2) + FEPS) + FEPS);
  float bd = t1 + t2 + t3;
  bd = fminf(fmaxf(bd, FEPS), 100.0f);
  float hd = sqrtf(1.0f - expf(-bd) + FEPS);
  return 1.0f - hd;
}

// ---------------------------------------------------------------------------
// Kernel 1: per-box derived quantities (SoA), conf (thresholded), label.
// ---------------------------------------------------------------------------
__global__ void prep_kernel(const float* __restrict__ boxes,
                            const float* __restrict__ scores,
                            float* __restrict__ X, float* __restrict__ Y,
                            float* __restrict__ VA, float* __restrict__ VB,
                            float* __restrict__ VC, float* __restrict__ DET,
                            float* __restrict__ CONF, int* __restrict__ LAB) {
#pragma clang fp contract(off)
  int idx = blockIdx.x * blockDim.x + threadIdx.x;
  if (idx >= BATCH * NBOX) return;
  const float* bx = boxes + (size_t)idx * 5;
  float w = bx[2], h = bx[3], r = bx[4];
  float a = w * w / 12.0f;
  float b = h * h / 12.0f;
  float cs = cosf(r), sn = sinf(r);
  float va = a * cs * cs + b * sn * sn;
  float vb = a * sn * sn + b * cs * cs;
  float vc = (a - b) * cs * sn;
  X[idx] = bx[0];
  Y[idx] = bx[1];
  VA[idx] = va;
  VB[idx] = vb;
  VC[idx] = vc;
  DET[idx] = fmaxf(va * vb - vc * vc, 0.0f);

  const float* sc = scores + (size_t)idx * NCLS;
  float best = sc[0];
  int lab = 0;
  for (int c = 1; c < NCLS; ++c) {
    float s = sc[c];
    if (s > best) { best = s; lab = c; }  // first-max semantics like argmax
  }
  CONF[idx] = (best < CONF_THR) ? 0.0f : best;
  LAB[idx] = lab;
}

// ---------------------------------------------------------------------------
// Kernel 2: cmax[b][j] = max_{i<j} iou(i, j)   (0 if empty; zeros included)
// One 256-thread block per (j, b).
// ---------------------------------------------------------------------------
__global__ void cmax_kernel(const float* __restrict__ X, const float* __restrict__ Y,
                            const float* __restrict__ VA, const float* __restrict__ VB,
                            const float* __restrict__ VC, const float* __restrict__ DET,
                            float* __restrict__ CMAX) {
#pragma clang fp contract(off)
  int j = blockIdx.x;
  int b = blockIdx.y;
  int t = threadIdx.x;
  int base = b * NBOX;
  float xj = X[base + j], yj = Y[base + j];
  float aj = VA[base + j], bj = VB[base + j], cj = VC[base + j], dj = DET[base + j];
  float m = 0.0f;  // triu zeros participate in the max
  for (int i = t; i < j; i += 256) {
    float v = probiou(X[base + i], Y[base + i], VA[base + i], VB[base + i],
                      VC[base + i], DET[base + i], xj, yj, aj, bj, cj, dj);
    m = fmaxf(m, v);
  }
  // reduce max over block (4 waves of 64)
  for (int off = 32; off > 0; off >>= 1) m = fmaxf(m, __shfl_down(m, off));
  __shared__ float red[4];
  int wave = t >> 6, lane = t & 63;
  if (lane == 0) red[wave] = m;
  __syncthreads();
  if (t == 0) {
    m = fmaxf(fmaxf(red[0], red[1]), fmaxf(red[2], red[3]));
    CMAX[base + j] = m;
  }
}

// ---------------------------------------------------------------------------
// Kernel 3: decay[b][j] = min_i exp(-(iou_triu(i,j)^2 - cmax[i]^2)/SIGMA)
// i >= j contributes exp(+cmax[i]^2/SIGMA) (iou=0 there) — must be included.
// One 256-thread block per (j, b).
// ---------------------------------------------------------------------------
__global__ void decay_kernel(const float* __restrict__ X, const float* __restrict__ Y,
                             const float* __restrict__ VA, const float* __restrict__ VB,
                             const float* __restrict__ VC, const float* __restrict__ DET,
                             const float* __restrict__ CMAX, float* __restrict__ DECAY) {
#pragma clang fp contract(off)
  int j = blockIdx.x;
  int b = blockIdx.y;
  int t = threadIdx.x;
  int base = b * NBOX;
  float xj = X[base + j], yj = Y[base + j];
  float aj = VA[base + j], bj = VB[base + j], cj = VC[base + j], dj = DET[base + j];
  float dmin = 3.4e38f;
  for (int i = t; i < NBOX; i += 256) {
    float ci = CMAX[base + i];
    float v = 0.0f;
    if (i < j) {
      v = probiou(X[base + i], Y[base + i], VA[base + i], VB[base + i],
                  VC[base + i], DET[base + i], xj, yj, aj, bj, cj, dj);
    }
    float term = expf(-(v * v - ci * ci) / 3.0f);
    dmin = fminf(dmin, term);
  }
  for (int off = 32; off > 0; off >>= 1) dmin = fminf(dmin, __shfl_down(dmin, off));
  __shared__ float red[4];
  int wave = t >> 6, lane = t & 63;
  if (lane == 0) red[wave] = dmin;
  __syncthreads();
  if (t == 0) {
    dmin = fminf(fminf(red[0], red[1]), fminf(red[2], red[3]));
    DECAY[base + j] = dmin;
  }
}

// ---------------------------------------------------------------------------
// Kernel 4: keep -> stable compaction -> batched outputs.
// One 1024-thread block per batch.
// Output layout (flat float32):
//   [0, B)                       : num (as float)
//   [B, B + B*M*5)               : boxes
//   [B + B*M*5, B + B*M*6)       : scores
//   [B + B*M*6, B + B*M*7)       : classes (as float)
// ---------------------------------------------------------------------------
__global__ void out_kernel(const float* __restrict__ boxes,
                           const float* __restrict__ CONF,
                           const int* __restrict__ LAB,
                           const float* __restrict__ DECAY,
                           float* __restrict__ out) {
  int b = blockIdx.x;
  int j = threadIdx.x;  // 0..1023
  int wave = j >> 6, lane = j & 63;
  int base = b * NBOX;
  float cf = CONF[base + j];
  float dc = DECAY[base + j];
  bool keep = (cf * dc) > KEEP_THR;

  unsigned long long mask = __ballot(keep);
  int wprefix = __popcll(mask & ((1ull << lane) - 1ull));
  __shared__ int wsum[16];
  __shared__ int wbase[16];
  __shared__ int s_total;
  if (lane == 0) wsum[wave] = __popcll(mask);
  __syncthreads();
  if (j == 0) {
    int acc = 0;
    for (int w = 0; w < 16; ++w) { wbase[w] = acc; acc += wsum[w]; }
    s_total = acc;
  }
  __syncthreads();
  int total = s_total;
  int num = min(total, MAXM);
  int pos = wbase[wave] + wprefix;

  float* o_num = out;
  float* o_box = out + BATCH;
  float* o_scr = out + BATCH + BATCH * MAXM * 5;
  float* o_cls = out + BATCH + BATCH * MAXM * 5 + BATCH * MAXM;

  if (j == 0) o_num[b] = (float)num;

  if (keep && pos < MAXM) {
    const float* src = boxes + (size_t)(base + j) * 5;
    float* dst = o_box + (size_t)(b * MAXM + pos) * 5;
#pragma unroll
    for (int k = 0; k < 5; ++k) dst[k] = src[k];
    o_scr[b * MAXM + pos] = cf;
    o_cls[b * MAXM + pos] = (float)LAB[base + j];
  }
  if (j >= num && j < MAXM) {
    float* dst = o_box + (size_t)(b * MAXM + j) * 5;
#pragma unroll
    for (int k = 0; k < 5; ++k) dst[k] = -1.0f;
    o_scr[b * MAXM + j] = -1.0f;
    o_cls[b * MAXM + j] = -1.0f;
  }
}

// ---------------------------------------------------------------------------
extern "C" void kernel_launch(void* const* d_in, const int* in_sizes, int n_in,
                              void* d_out, int out_size, void* d_ws, size_t ws_size,
                              hipStream_t stream) {
  const float* boxes = (const float*)d_in[0];   // [B, N, 5]
  const float* scores = (const float*)d_in[1];  // [B, N, C]
  float* out = (float*)d_out;

  const int BN = BATCH * NBOX;
  float* f = (float*)d_ws;
  float* X = f + 0 * BN;
  float* Y = f + 1 * BN;
  float* VA = f + 2 * BN;
  float* VB = f + 3 * BN;
  float* VC = f + 4 * BN;
  float* DET = f + 5 * BN;
  float* CONF = f + 6 * BN;
  float* CMAX = f + 7 * BN;
  float* DECAY = f + 8 * BN;
  int* LAB = (int*)(f + 9 * BN);

  prep_kernel<<<(BN + 255) / 256, 256, 0, stream>>>(boxes, scores, X, Y, VA, VB,
                                                    VC, DET, CONF, LAB);
  cmax_kernel<<<dim3(NBOX, BATCH), 256, 0, stream>>>(X, Y, VA, VB, VC, DET, CMAX);
  decay_kernel<<<dim3(NBOX, BATCH), 256, 0, stream>>>(X, Y, VA, VB, VC, DET, CMAX,
                                                      DECAY);
  out_kernel<<<BATCH, 1024, 0, stream>>>(boxes, CONF, LAB, DECAY, out);
}

// Round 2
// 101.565 us; speedup vs baseline: 1.6206x; 1.6206x over previous
//
#include <hip/hip_runtime.h>

// Problem constants (match reference)
#define BATCH 32
#define NBOX 1024
#define NCLS 15
#define MAXM 300
#define CONF_THR 0.1f
#define KEEP_THR 0.2f
#define FEPS 1e-7f
#define TRI_PER_B 523776  // NBOX*(NBOX-1)/2

// ---------------------------------------------------------------------------
// ProbIoU between box i (1) and box j (2), reference op order exactly,
// FP contraction disabled to match numpy float32 semantics.
// ---------------------------------------------------------------------------
__device__ __forceinline__ float probiou(
    float x1, float y1, float a1, float b1, float c1, float det1,
    float x2, float y2, float a2, float b2, float c2, float det2) {
#pragma clang fp contract(off)
  float dx = x1 - x2;
  float dy = y1 - y2;
  float sa = a1 + a2;
  float sb = b1 + b2;
  float sc = c1 + c2;
  float denom = sa * sb - sc * sc + FEPS;
  float t1 = (sa * dy * dy + sb * dx * dx) / denom * 0.25f;
  float t2 = (sc * (-dx) * dy) / denom * 0.5f;
  float t3 = 0.5f * logf(denom / (4.0f * sqrtf(det1 * det2) + FEPS) + FEPS);
  float bd = t1 + t2 + t3;
  bd = fminf(fmaxf(bd, FEPS), 100.0f);
  float hd = sqrtf(1.0f - expf(-bd) + FEPS);
  return 1.0f - hd;
}

__device__ __forceinline__ float block_max256(float m, float* red) {
  for (int off = 32; off > 0; off >>= 1) m = fmaxf(m, __shfl_down(m, off));
  int t = threadIdx.x, wave = t >> 6, lane = t & 63;
  if (lane == 0) red[wave] = m;
  __syncthreads();
  return fmaxf(fmaxf(red[0], red[1]), fmaxf(red[2], red[3]));
}

// ---------------------------------------------------------------------------
// Kernel 1: per-box derived SoA (vectorized): G1=(x,y,va,vb), G2=(vc,det),
// conf (thresholded), label.
// ---------------------------------------------------------------------------
__global__ void prep_kernel(const float* __restrict__ boxes,
                            const float* __restrict__ scores,
                            float4* __restrict__ G1, float2* __restrict__ G2,
                            float* __restrict__ CONF, int* __restrict__ LAB) {
#pragma clang fp contract(off)
  int idx = blockIdx.x * blockDim.x + threadIdx.x;
  if (idx >= BATCH * NBOX) return;
  const float* bx = boxes + (size_t)idx * 5;
  float w = bx[2], h = bx[3], r = bx[4];
  float a = w * w / 12.0f;
  float b = h * h / 12.0f;
  float cs = cosf(r), sn = sinf(r);
  float va = a * cs * cs + b * sn * sn;
  float vb = a * sn * sn + b * cs * cs;
  float vc = (a - b) * cs * sn;
  G1[idx] = make_float4(bx[0], bx[1], va, vb);
  G2[idx] = make_float2(vc, fmaxf(va * vb - vc * vc, 0.0f));

  const float* sc = scores + (size_t)idx * NCLS;
  float best = sc[0];
  int lab = 0;
  for (int c = 1; c < NCLS; ++c) {
    float s = sc[c];
    if (s > best) { best = s; lab = c; }
  }
  CONF[idx] = (best < CONF_THR) ? 0.0f : best;
  LAB[idx] = lab;
}

// ---------------------------------------------------------------------------
// Kernel 2 (pass 1): cmax[b][j] = max_{i<j} iou(i,j) (0 floor from triu zeros)
// STORE variant also writes iou^2 into packed triangular VSQ.
// ---------------------------------------------------------------------------
template <bool STORE>
__global__ void pass1_kernel(const float4* __restrict__ G1,
                             const float2* __restrict__ G2,
                             float* __restrict__ CMAX,
                             float* __restrict__ VSQ) {
#pragma clang fp contract(off)
  int j = blockIdx.x;
  int b = blockIdx.y;
  int t = threadIdx.x;
  int base = b * NBOX;
  float4 pj = G1[base + j];
  float2 qj = G2[base + j];
  size_t row = (size_t)b * TRI_PER_B + ((size_t)j * (j - 1)) / 2;
  float m = 0.0f;  // triu zeros participate in the max
  for (int i = t; i < j; i += 256) {
    float4 pi = G1[base + i];
    float2 qi = G2[base + i];
    float v = probiou(pi.x, pi.y, pi.z, pi.w, qi.x, qi.y,
                      pj.x, pj.y, pj.z, pj.w, qj.x, qj.y);
    if (STORE) VSQ[row + i] = v * v;
    m = fmaxf(m, v);
  }
  __shared__ float red[4];
  m = block_max256(m, red);
  if (t == 0) CMAX[base + j] = m;
}

// ---------------------------------------------------------------------------
// Kernel 3: CI2[b][i] = cmax^2; SUFF[b][j] = min_{i>=j} CI2[b][i] (LDS scan)
// ---------------------------------------------------------------------------
__global__ void suffix_kernel(const float* __restrict__ CMAX,
                              float* __restrict__ CI2,
                              float* __restrict__ SUFF) {
#pragma clang fp contract(off)
  int b = blockIdx.x;
  int j = threadIdx.x;  // 1024 threads
  __shared__ float s[NBOX];
  float c = CMAX[b * NBOX + j];
  float c2 = c * c;
  CI2[b * NBOX + j] = c2;
  s[j] = c2;
  __syncthreads();
  for (int off = 1; off < NBOX; off <<= 1) {
    float v = s[j];
    if (j + off < NBOX) v = fminf(v, s[j + off]);
    __syncthreads();
    s[j] = v;
    __syncthreads();
  }
  SUFF[b * NBOX + j] = s[j];
}

// ---------------------------------------------------------------------------
// Kernel 4 (pass 2): decay[b][j] = exp(-(tmax)/SIGMA) where
//   tmax = max( max_{i<j}(iou^2 - ci2[i]), -SUFF[j] )
// Exact-value equivalent of the reference's min-of-exp (exp is monotone).
// ---------------------------------------------------------------------------
__global__ void pass2_store_kernel(const float* __restrict__ VSQ,
                                   const float* __restrict__ CI2,
                                   const float* __restrict__ SUFF,
                                   float* __restrict__ DECAY) {
#pragma clang fp contract(off)
  int j = blockIdx.x;
  int b = blockIdx.y;
  int t = threadIdx.x;
  int base = b * NBOX;
  size_t row = (size_t)b * TRI_PER_B + ((size_t)j * (j - 1)) / 2;
  float m = -3.402823466e38f;
  for (int i = t; i < j; i += 256) {
    m = fmaxf(m, VSQ[row + i] - CI2[base + i]);
  }
  __shared__ float red[4];
  m = block_max256(m, red);
  if (t == 0) {
    float tmax = fmaxf(m, -SUFF[base + j]);
    DECAY[base + j] = expf((-tmax) / 3.0f);
  }
}

// Fallback when ws too small for VSQ: recompute iou (still no per-pair exp).
__global__ void pass2_recompute_kernel(const float4* __restrict__ G1,
                                       const float2* __restrict__ G2,
                                       const float* __restrict__ CI2,
                                       const float* __restrict__ SUFF,
                                       float* __restrict__ DECAY) {
#pragma clang fp contract(off)
  int j = blockIdx.x;
  int b = blockIdx.y;
  int t = threadIdx.x;
  int base = b * NBOX;
  float4 pj = G1[base + j];
  float2 qj = G2[base + j];
  float m = -3.402823466e38f;
  for (int i = t; i < j; i += 256) {
    float4 pi = G1[base + i];
    float2 qi = G2[base + i];
    float v = probiou(pi.x, pi.y, pi.z, pi.w, qi.x, qi.y,
                      pj.x, pj.y, pj.z, pj.w, qj.x, qj.y);
    float vv = v * v;           // separate mul, then sub (no fma) = ref order
    m = fmaxf(m, vv - CI2[base + i]);
  }
  __shared__ float red[4];
  m = block_max256(m, red);
  if (t == 0) {
    float tmax = fmaxf(m, -SUFF[base + j]);
    DECAY[base + j] = expf((-tmax) / 3.0f);
  }
}

// ---------------------------------------------------------------------------
// Kernel 5: keep -> stable compaction -> batched outputs.
// ---------------------------------------------------------------------------
__global__ void out_kernel(const float* __restrict__ boxes,
                           const float* __restrict__ CONF,
                           const int* __restrict__ LAB,
                           const float* __restrict__ DECAY,
                           float* __restrict__ out) {
  int b = blockIdx.x;
  int j = threadIdx.x;  // 0..1023
  int wave = j >> 6, lane = j & 63;
  int base = b * NBOX;
  float cf = CONF[base + j];
  float dc = DECAY[base + j];
  bool keep = (cf * dc) > KEEP_THR;

  unsigned long long mask = __ballot(keep);
  int wprefix = __popcll(mask & ((1ull << lane) - 1ull));
  __shared__ int wsum[16];
  __shared__ int wbase[16];
  __shared__ int s_total;
  if (lane == 0) wsum[wave] = __popcll(mask);
  __syncthreads();
  if (j == 0) {
    int acc = 0;
    for (int w = 0; w < 16; ++w) { wbase[w] = acc; acc += wsum[w]; }
    s_total = acc;
  }
  __syncthreads();
  int total = s_total;
  int num = min(total, MAXM);
  int pos = wbase[wave] + wprefix;

  float* o_num = out;
  float* o_box = out + BATCH;
  float* o_scr = out + BATCH + BATCH * MAXM * 5;
  float* o_cls = out + BATCH + BATCH * MAXM * 5 + BATCH * MAXM;

  if (j == 0) o_num[b] = (float)num;

  if (keep && pos < MAXM) {
    const float* src = boxes + (size_t)(base + j) * 5;
    float* dst = o_box + (size_t)(b * MAXM + pos) * 5;
#pragma unroll
    for (int k = 0; k < 5; ++k) dst[k] = src[k];
    o_scr[b * MAXM + pos] = cf;
    o_cls[b * MAXM + pos] = (float)LAB[base + j];
  }
  if (j >= num && j < MAXM) {
    float* dst = o_box + (size_t)(b * MAXM + j) * 5;
#pragma unroll
    for (int k = 0; k < 5; ++k) dst[k] = -1.0f;
    o_scr[b * MAXM + j] = -1.0f;
    o_cls[b * MAXM + j] = -1.0f;
  }
}

// ---------------------------------------------------------------------------
extern "C" void kernel_launch(void* const* d_in, const int* in_sizes, int n_in,
                              void* d_out, int out_size, void* d_ws, size_t ws_size,
                              hipStream_t stream) {
  const float* boxes = (const float*)d_in[0];   // [B, N, 5]
  const float* scores = (const float*)d_in[1];  // [B, N, C]
  float* out = (float*)d_out;

  const int BN = BATCH * NBOX;
  char* w = (char*)d_ws;
  float4* G1 = (float4*)(w);                         // 524288 B
  float2* G2 = (float2*)(w + 524288);                // 262144 B
  float* CONF = (float*)(w + 786432);                // 131072 B
  float* CMAX = (float*)(w + 917504);                // 131072 B
  float* CI2  = (float*)(w + 1048576);               // 131072 B
  float* SUFF = (float*)(w + 1179648);               // 131072 B
  float* DECAY= (float*)(w + 1310720);               // 131072 B
  int*   LAB  = (int*)  (w + 1441792);               // 131072 B
  float* VSQ  = (float*)(w + 1572864);               // 67,043,328 B (packed tri)
  const size_t need_store = 1572864 + (size_t)BATCH * TRI_PER_B * 4;
  const bool store_path = (ws_size >= need_store);

  prep_kernel<<<(BN + 255) / 256, 256, 0, stream>>>(boxes, scores, G1, G2, CONF, LAB);

  if (store_path) {
    pass1_kernel<true><<<dim3(NBOX, BATCH), 256, 0, stream>>>(G1, G2, CMAX, VSQ);
  } else {
    pass1_kernel<false><<<dim3(NBOX, BATCH), 256, 0, stream>>>(G1, G2, CMAX, VSQ);
  }

  suffix_kernel<<<BATCH, NBOX, 0, stream>>>(CMAX, CI2, SUFF);

  if (store_path) {
    pass2_store_kernel<<<dim3(NBOX, BATCH), 256, 0, stream>>>(VSQ, CI2, SUFF, DECAY);
  } else {
    pass2_recompute_kernel<<<dim3(NBOX, BATCH), 256, 0, stream>>>(G1, G2, CI2, SUFF, DECAY);
  }

  out_kernel<<<BATCH, 1024, 0, stream>>>(boxes, CONF, LAB, DECAY, out);
}

// Round 3
// 98.423 us; speedup vs baseline: 1.6723x; 1.0319x over previous
//
#include <hip/hip_runtime.h>

// Problem constants (match reference)
#define BATCH 32
#define NBOX 1024
#define NCLS 15
#define MAXM 300
#define CONF_THR 0.1f
#define KEEP_THR 0.2f
#define FEPS 1e-7f
#define TRI_PER_B 523776  // NBOX*(NBOX-1)/2
#define TPB1 128          // pass1 block size (tail waste 25% -> 12%)

// ---------------------------------------------------------------------------
// Clipped Bhattacharyya distance bd, reference op order exactly, contraction
// off. iou = 1 - sqrt(1 - exp(-bd) + eps) is monotone DECREASING in bd, so
// max iou == iou(min bd) and per-pair exp/sqrt can be deferred.
// ---------------------------------------------------------------------------
__device__ __forceinline__ float pair_bd(
    float x1, float y1, float a1, float b1, float c1, float det1,
    float x2, float y2, float a2, float b2, float c2, float det2) {
#pragma clang fp contract(off)
  float dx = x1 - x2;
  float dy = y1 - y2;
  float sa = a1 + a2;
  float sb = b1 + b2;
  float sc = c1 + c2;
  float denom = sa * sb - sc * sc + FEPS;
  float t1 = (sa * dy * dy + sb * dx * dx) / denom * 0.25f;
  float t2 = (sc * (-dx) * dy) / denom * 0.5f;
  float t3 = 0.5f * logf(denom / (4.0f * sqrtf(det1 * det2) + FEPS) + FEPS);
  float bd = t1 + t2 + t3;
  return fminf(fmaxf(bd, FEPS), 100.0f);
}

// bd -> iou with the reference's exact op chain.
__device__ __forceinline__ float bd_to_iou(float bd) {
#pragma clang fp contract(off)
  float hd = sqrtf(1.0f - expf(-bd) + FEPS);
  return 1.0f - hd;
}

__device__ __forceinline__ float wave_min64(float m) {
  for (int off = 32; off > 0; off >>= 1) m = fminf(m, __shfl_down(m, off));
  return m;
}
__device__ __forceinline__ float block_max256(float m, float* red) {
  for (int off = 32; off > 0; off >>= 1) m = fmaxf(m, __shfl_down(m, off));
  int t = threadIdx.x, wave = t >> 6, lane = t & 63;
  if (lane == 0) red[wave] = m;
  __syncthreads();
  return fmaxf(fmaxf(red[0], red[1]), fmaxf(red[2], red[3]));
}

// ---------------------------------------------------------------------------
// Kernel 1: per-box derived SoA: G1=(x,y,va,vb), G2=(vc,det), conf, label.
// ---------------------------------------------------------------------------
__global__ void prep_kernel(const float* __restrict__ boxes,
                            const float* __restrict__ scores,
                            float4* __restrict__ G1, float2* __restrict__ G2,
                            float* __restrict__ CONF, int* __restrict__ LAB) {
#pragma clang fp contract(off)
  int idx = blockIdx.x * blockDim.x + threadIdx.x;
  if (idx >= BATCH * NBOX) return;
  const float* bx = boxes + (size_t)idx * 5;
  float w = bx[2], h = bx[3], r = bx[4];
  float a = w * w / 12.0f;
  float b = h * h / 12.0f;
  float cs = cosf(r), sn = sinf(r);
  float va = a * cs * cs + b * sn * sn;
  float vb = a * sn * sn + b * cs * cs;
  float vc = (a - b) * cs * sn;
  G1[idx] = make_float4(bx[0], bx[1], va, vb);
  G2[idx] = make_float2(vc, fmaxf(va * vb - vc * vc, 0.0f));

  const float* sc = scores + (size_t)idx * NCLS;
  float best = sc[0];
  int lab = 0;
  for (int c = 1; c < NCLS; ++c) {
    float s = sc[c];
    if (s > best) { best = s; lab = c; }
  }
  CONF[idx] = (best < CONF_THR) ? 0.0f : best;
  LAB[idx] = lab;
}

// ---------------------------------------------------------------------------
// Kernel 2 (pass 1): per pair (i<j) compute clipped bd; store it; fmin-reduce
// per row j -> BDMIN. No per-pair exp/sqrt. 128-thread blocks.
// ---------------------------------------------------------------------------
template <bool STORE>
__global__ void pass1_kernel(const float4* __restrict__ G1,
                             const float2* __restrict__ G2,
                             float* __restrict__ BDMIN,
                             float* __restrict__ BD) {
#pragma clang fp contract(off)
  int j = blockIdx.x;
  int b = blockIdx.y;
  int t = threadIdx.x;
  int base = b * NBOX;
  float4 pj = G1[base + j];
  float2 qj = G2[base + j];
  size_t row = (size_t)b * TRI_PER_B + ((size_t)j * (j - 1)) / 2;
  float m = 3.402823466e38f;
  for (int i = t; i < j; i += TPB1) {
    float4 pi = G1[base + i];
    float2 qi = G2[base + i];
    float bd = pair_bd(pi.x, pi.y, pi.z, pi.w, qi.x, qi.y,
                       pj.x, pj.y, pj.z, pj.w, qj.x, qj.y);
    if (STORE) BD[row + i] = bd;
    m = fminf(m, bd);
  }
  m = wave_min64(m);
  __shared__ float red[2];
  int wave = t >> 6, lane = t & 63;
  if (lane == 0) red[wave] = m;
  __syncthreads();
  if (t == 0) BDMIN[base + j] = fminf(red[0], red[1]);
}

// ---------------------------------------------------------------------------
// Kernel 3: cmax_j = max(0, iou(BDMIN_j)) (0-floor from triu zeros; j=0 empty
// column -> 0). CI2 = cmax^2; SUFF[j] = min_{i>=j} CI2[i] (LDS suffix scan).
// ---------------------------------------------------------------------------
__global__ void suffix_kernel(const float* __restrict__ BDMIN,
                              float* __restrict__ CI2,
                              float* __restrict__ SUFF) {
#pragma clang fp contract(off)
  int b = blockIdx.x;
  int j = threadIdx.x;  // 1024 threads
  __shared__ float s[NBOX];
  float cmax = 0.0f;
  if (j > 0) cmax = fmaxf(0.0f, bd_to_iou(BDMIN[b * NBOX + j]));
  float c2 = cmax * cmax;
  CI2[b * NBOX + j] = c2;
  s[j] = c2;
  __syncthreads();
  for (int off = 1; off < NBOX; off <<= 1) {
    float v = s[j];
    if (j + off < NBOX) v = fminf(v, s[j + off]);
    __syncthreads();
    s[j] = v;
    __syncthreads();
  }
  SUFF[b * NBOX + j] = s[j];
}

// ---------------------------------------------------------------------------
// Kernel 4 (pass 2): decay[b][j] = exp(-tmax/SIGMA),
//   tmax = max( max_{i<j}(iou(bd)^2 - ci2[i]), -SUFF[j] ).
// exp is monotone -> exact-value equivalent of the reference's min-of-exp.
// The iou chain here is bit-identical to the reference per-pair chain.
// ---------------------------------------------------------------------------
__global__ void pass2_store_kernel(const float* __restrict__ BD,
                                   const float* __restrict__ CI2,
                                   const float* __restrict__ SUFF,
                                   float* __restrict__ DECAY) {
#pragma clang fp contract(off)
  int j = blockIdx.x;
  int b = blockIdx.y;
  int t = threadIdx.x;
  int base = b * NBOX;
  size_t row = (size_t)b * TRI_PER_B + ((size_t)j * (j - 1)) / 2;
  float m = -3.402823466e38f;
  for (int i = t; i < j; i += 256) {
    float v = bd_to_iou(BD[row + i]);
    float vv = v * v;
    m = fmaxf(m, vv - CI2[base + i]);
  }
  __shared__ float red[4];
  m = block_max256(m, red);
  if (t == 0) {
    float tmax = fmaxf(m, -SUFF[base + j]);
    DECAY[base + j] = expf((-tmax) / 3.0f);
  }
}

// Fallback when ws too small for BD: recompute bd per pair.
__global__ void pass2_recompute_kernel(const float4* __restrict__ G1,
                                       const float2* __restrict__ G2,
                                       const float* __restrict__ CI2,
                                       const float* __restrict__ SUFF,
                                       float* __restrict__ DECAY) {
#pragma clang fp contract(off)
  int j = blockIdx.x;
  int b = blockIdx.y;
  int t = threadIdx.x;
  int base = b * NBOX;
  float4 pj = G1[base + j];
  float2 qj = G2[base + j];
  float m = -3.402823466e38f;
  for (int i = t; i < j; i += 256) {
    float4 pi = G1[base + i];
    float2 qi = G2[base + i];
    float bd = pair_bd(pi.x, pi.y, pi.z, pi.w, qi.x, qi.y,
                       pj.x, pj.y, pj.z, pj.w, qj.x, qj.y);
    float v = bd_to_iou(bd);
    float vv = v * v;
    m = fmaxf(m, vv - CI2[base + i]);
  }
  __shared__ float red[4];
  m = block_max256(m, red);
  if (t == 0) {
    float tmax = fmaxf(m, -SUFF[base + j]);
    DECAY[base + j] = expf((-tmax) / 3.0f);
  }
}

// ---------------------------------------------------------------------------
// Kernel 5: keep -> stable compaction -> batched outputs.
// ---------------------------------------------------------------------------
__global__ void out_kernel(const float* __restrict__ boxes,
                           const float* __restrict__ CONF,
                           const int* __restrict__ LAB,
                           const float* __restrict__ DECAY,
                           float* __restrict__ out) {
  int b = blockIdx.x;
  int j = threadIdx.x;  // 0..1023
  int wave = j >> 6, lane = j & 63;
  int base = b * NBOX;
  float cf = CONF[base + j];
  float dc = DECAY[base + j];
  bool keep = (cf * dc) > KEEP_THR;

  unsigned long long mask = __ballot(keep);
  int wprefix = __popcll(mask & ((1ull << lane) - 1ull));
  __shared__ int wsum[16];
  __shared__ int wbase[16];
  __shared__ int s_total;
  if (lane == 0) wsum[wave] = __popcll(mask);
  __syncthreads();
  if (j == 0) {
    int acc = 0;
    for (int w = 0; w < 16; ++w) { wbase[w] = acc; acc += wsum[w]; }
    s_total = acc;
  }
  __syncthreads();
  int total = s_total;
  int num = min(total, MAXM);
  int pos = wbase[wave] + wprefix;

  float* o_num = out;
  float* o_box = out + BATCH;
  float* o_scr = out + BATCH + BATCH * MAXM * 5;
  float* o_cls = out + BATCH + BATCH * MAXM * 5 + BATCH * MAXM;

  if (j == 0) o_num[b] = (float)num;

  if (keep && pos < MAXM) {
    const float* src = boxes + (size_t)(base + j) * 5;
    float* dst = o_box + (size_t)(b * MAXM + pos) * 5;
#pragma unroll
    for (int k = 0; k < 5; ++k) dst[k] = src[k];
    o_scr[b * MAXM + pos] = cf;
    o_cls[b * MAXM + pos] = (float)LAB[base + j];
  }
  if (j >= num && j < MAXM) {
    float* dst = o_box + (size_t)(b * MAXM + j) * 5;
#pragma unroll
    for (int k = 0; k < 5; ++k) dst[k] = -1.0f;
    o_scr[b * MAXM + j] = -1.0f;
    o_cls[b * MAXM + j] = -1.0f;
  }
}

// ---------------------------------------------------------------------------
extern "C" void kernel_launch(void* const* d_in, const int* in_sizes, int n_in,
                              void* d_out, int out_size, void* d_ws, size_t ws_size,
                              hipStream_t stream) {
  const float* boxes = (const float*)d_in[0];   // [B, N, 5]
  const float* scores = (const float*)d_in[1];  // [B, N, C]
  float* out = (float*)d_out;

  const int BN = BATCH * NBOX;
  char* w = (char*)d_ws;
  float4* G1 = (float4*)(w);                         // 524288 B
  float2* G2 = (float2*)(w + 524288);                // 262144 B
  float* CONF = (float*)(w + 786432);                // 131072 B
  float* BDMIN = (float*)(w + 917504);               // 131072 B
  float* CI2  = (float*)(w + 1048576);               // 131072 B
  float* SUFF = (float*)(w + 1179648);               // 131072 B
  float* DECAY= (float*)(w + 1310720);               // 131072 B
  int*   LAB  = (int*)  (w + 1441792);               // 131072 B
  float* BD   = (float*)(w + 1572864);               // 67,043,328 B (packed tri)
  const size_t need_store = 1572864 + (size_t)BATCH * TRI_PER_B * 4;
  const bool store_path = (ws_size >= need_store);

  prep_kernel<<<(BN + 255) / 256, 256, 0, stream>>>(boxes, scores, G1, G2, CONF, LAB);

  if (store_path) {
    pass1_kernel<true><<<dim3(NBOX, BATCH), TPB1, 0, stream>>>(G1, G2, BDMIN, BD);
  } else {
    pass1_kernel<false><<<dim3(NBOX, BATCH), TPB1, 0, stream>>>(G1, G2, BDMIN, BD);
  }

  suffix_kernel<<<BATCH, NBOX, 0, stream>>>(BDMIN, CI2, SUFF);

  if (store_path) {
    pass2_store_kernel<<<dim3(NBOX, BATCH), 256, 0, stream>>>(BD, CI2, SUFF, DECAY);
  } else {
    pass2_recompute_kernel<<<dim3(NBOX, BATCH), 256, 0, stream>>>(G1, G2, CI2, SUFF, DECAY);
  }

  out_kernel<<<BATCH, 1024, 0, stream>>>(boxes, CONF, LAB, DECAY, out);
}

// Round 4
// 76.220 us; speedup vs baseline: 2.1595x; 1.2913x over previous
//
#include <hip/hip_runtime.h>

// Problem constants (match reference)
#define BATCH 32
#define NBOX 1024
#define NCLS 15
#define MAXM 300
#define CONF_THR 0.1f
#define KEEP_THR 0.2f
#define FEPS 1e-7f
#define TRI_PER_B 523776  // NBOX*(NBOX-1)/2
#define FAR_T 19.0f       // certificate threshold (sound: guarantees iou==0.0f)

// ---------------------------------------------------------------------------
// Full reference ProbIoU chain (box i = operand 1, box j = operand 2),
// bit-exact op order, contraction off.
// ---------------------------------------------------------------------------
__device__ __forceinline__ float pair_iou(
    float x1, float y1, float a1, float b1, float c1, float det1,
    float x2, float y2, float a2, float b2, float c2, float det2) {
#pragma clang fp contract(off)
  float dx = x1 - x2;
  float dy = y1 - y2;
  float sa = a1 + a2;
  float sb = b1 + b2;
  float sc = c1 + c2;
  float denom = sa * sb - sc * sc + FEPS;
  float t1 = (sa * dy * dy + sb * dx * dx) / denom * 0.25f;
  float t2 = (sc * (-dx) * dy) / denom * 0.5f;
  float t3 = 0.5f * logf(denom / (4.0f * sqrtf(det1 * det2) + FEPS) + FEPS);
  float bd = t1 + t2 + t3;
  bd = fminf(fmaxf(bd, FEPS), 100.0f);
  float hd = sqrtf(1.0f - expf(-bd) + FEPS);
  return 1.0f - hd;
}

// ---------------------------------------------------------------------------
// Kernel 1: per-box derived SoA: G1=(x,y,va,vb), VC, DET, conf, label.
// ---------------------------------------------------------------------------
__global__ void prep_kernel(const float* __restrict__ boxes,
                            const float* __restrict__ scores,
                            float4* __restrict__ G1, float* __restrict__ VC,
                            float* __restrict__ DET, float* __restrict__ CONF,
                            int* __restrict__ LAB) {
#pragma clang fp contract(off)
  int idx = blockIdx.x * blockDim.x + threadIdx.x;
  if (idx >= BATCH * NBOX) return;
  const float* bx = boxes + (size_t)idx * 5;
  float w = bx[2], h = bx[3], r = bx[4];
  float a = w * w / 12.0f;
  float b = h * h / 12.0f;
  float cs = cosf(r), sn = sinf(r);
  float va = a * cs * cs + b * sn * sn;
  float vb = a * sn * sn + b * cs * cs;
  float vc = (a - b) * cs * sn;
  G1[idx] = make_float4(bx[0], bx[1], va, vb);
  VC[idx] = vc;
  DET[idx] = fmaxf(va * vb - vc * vc, 0.0f);

  const float* sc = scores + (size_t)idx * NCLS;
  float best = sc[0];
  int lab = 0;
  for (int c = 1; c < NCLS; ++c) {
    float s = sc[c];
    if (s > best) { best = s; lab = c; }
  }
  CONF[idx] = (best < CONF_THR) ? 0.0f : best;
  LAB[idx] = lab;
}

// ---------------------------------------------------------------------------
// Kernel 2: certificate + compaction. Row j, batch b. 128 threads = 2 waves,
// each wave owns an independent i-segment (no cross-wave sync needed).
// Certified-far pairs have iou == 0.0f exactly -> dropped. Others' indices
// are ballot-compacted into NIDX (u16) in the packed-triangular row.
// ---------------------------------------------------------------------------
__global__ void certify_kernel(const float4* __restrict__ G1,
                               const float* __restrict__ VC,
                               unsigned short* __restrict__ NIDX,
                               unsigned short* __restrict__ NCNT) {
#pragma clang fp contract(off)
  int j = blockIdx.x;
  int b = blockIdx.y;
  int w = threadIdx.x >> 6, lane = threadIdx.x & 63;
  int base = b * NBOX;
  float4 pj = G1[base + j];
  float vcj = VC[base + j];
  int h = (j + 1) >> 1;                // segment split
  int lo = w ? h : 0, hi = w ? j : h;
  size_t tri = (size_t)b * TRI_PER_B + ((size_t)j * (j - 1)) / 2;
  unsigned short* slot = NIDX + tri + (w ? h : 0);
  int cnt = 0;
  for (int i = lo + lane; i < hi; i += 64) {
    float4 pi = G1[base + i];
    float vci = VC[base + i];
    float dx = pi.x - pj.x, dy = pi.y - pj.y;
    float sa = pi.z + pj.z, sb = pi.w + pj.w, sc = vci + vcj;
    float denom = sa * sb - sc * sc + FEPS;
    float lhs = 0.25f * (sa * (dy * dy) + sb * (dx * dx)) - 0.5f * (sc * (dx * dy));
    bool nearp = !(lhs >= FAR_T * denom);
    unsigned long long mask = __ballot(nearp);
    if (nearp) {
      int p = __popcll(mask & ((1ull << lane) - 1ull));
      slot[cnt + p] = (unsigned short)i;
    }
    cnt += __popcll(mask);
  }
  if (lane == 0) NCNT[(base + j) * 2 + w] = (unsigned short)cnt;
}

// ---------------------------------------------------------------------------
// Kernel 3: cmax over compacted near pairs (far pairs are exactly 0 <= floor).
// Optionally stores iou values compactly for the decay pass.
// ---------------------------------------------------------------------------
template <bool STORE_IOU>
__global__ void cmax_kernel(const float4* __restrict__ G1,
                            const float* __restrict__ VC,
                            const float* __restrict__ DET,
                            const unsigned short* __restrict__ NIDX,
                            const unsigned short* __restrict__ NCNT,
                            float* __restrict__ CMAX,
                            float* __restrict__ IOUC) {
#pragma clang fp contract(off)
  int j = blockIdx.x;
  int b = blockIdx.y;
  int w = threadIdx.x >> 6, lane = threadIdx.x & 63;
  int base = b * NBOX;
  float4 pj = G1[base + j];
  float vcj = VC[base + j], dj = DET[base + j];
  int h = (j + 1) >> 1;
  int off = w ? h : 0;
  int n = NCNT[(base + j) * 2 + w];
  size_t tri = (size_t)b * TRI_PER_B + ((size_t)j * (j - 1)) / 2;
  const unsigned short* sl = NIDX + tri + off;
  float m = 0.0f;  // triu-zero floor
  for (int k = lane; k < n; k += 64) {
    int i = sl[k];
    float4 pi = G1[base + i];
    float v = pair_iou(pi.x, pi.y, pi.z, pi.w, VC[base + i], DET[base + i],
                       pj.x, pj.y, pj.z, pj.w, vcj, dj);
    if (STORE_IOU) IOUC[tri + off + k] = v;
    m = fmaxf(m, v);
  }
  for (int o = 32; o > 0; o >>= 1) m = fmaxf(m, __shfl_down(m, o));
  __shared__ float red[2];
  if (lane == 0) red[w] = m;
  __syncthreads();
  if (threadIdx.x == 0) CMAX[base + j] = fmaxf(red[0], red[1]);
}

// ---------------------------------------------------------------------------
// Kernel 4: CI2 = cmax^2; PREMIN[b] = min_i CI2 (replaces the suffix scan:
// far/triu candidates -ci2_i are all dominated by or equal to -min ci2).
// ---------------------------------------------------------------------------
__global__ void minci2_kernel(const float* __restrict__ CMAX,
                              float* __restrict__ CI2,
                              float* __restrict__ PREMIN) {
#pragma clang fp contract(off)
  int b = blockIdx.x;
  int j = threadIdx.x;  // 1024
  float c = CMAX[b * NBOX + j];
  float c2 = c * c;
  CI2[b * NBOX + j] = c2;
  float m = c2;
  for (int o = 32; o > 0; o >>= 1) m = fminf(m, __shfl_down(m, o));
  __shared__ float red[16];
  int wv = j >> 6, ln = j & 63;
  if (ln == 0) red[wv] = m;
  __syncthreads();
  if (j == 0) {
    float mm = red[0];
    for (int k = 1; k < 16; ++k) mm = fminf(mm, red[k]);
    PREMIN[b] = mm;
  }
}

// ---------------------------------------------------------------------------
// Kernel 5: decay[b][j] = expf(-tmax/3),
//   tmax = max( max_{near i<j}(iou^2 - ci2_i), -PREMIN[b] ).
// Exact-value equivalent of the reference min-of-exp (exp monotone; far
// pairs' iou == 0.0f exactly).
// ---------------------------------------------------------------------------
template <bool LOAD_IOU>
__global__ void decay_kernel(const float4* __restrict__ G1,
                             const float* __restrict__ VC,
                             const float* __restrict__ DET,
                             const unsigned short* __restrict__ NIDX,
                             const unsigned short* __restrict__ NCNT,
                             const float* __restrict__ CI2,
                             const float* __restrict__ PREMIN,
                             const float* __restrict__ IOUC,
                             float* __restrict__ DECAY) {
#pragma clang fp contract(off)
  int j = blockIdx.x;
  int b = blockIdx.y;
  int w = threadIdx.x >> 6, lane = threadIdx.x & 63;
  int base = b * NBOX;
  float4 pj = G1[base + j];
  float vcj = VC[base + j], dj = DET[base + j];
  int h = (j + 1) >> 1;
  int off = w ? h : 0;
  int n = NCNT[(base + j) * 2 + w];
  size_t tri = (size_t)b * TRI_PER_B + ((size_t)j * (j - 1)) / 2;
  const unsigned short* sl = NIDX + tri + off;
  float m = -PREMIN[b];
  for (int k = lane; k < n; k += 64) {
    int i = sl[k];
    float v;
    if (LOAD_IOU) {
      v = IOUC[tri + off + k];
    } else {
      float4 pi = G1[base + i];
      v = pair_iou(pi.x, pi.y, pi.z, pi.w, VC[base + i], DET[base + i],
                   pj.x, pj.y, pj.z, pj.w, vcj, dj);
    }
    float vv = v * v;
    m = fmaxf(m, vv - CI2[base + i]);
  }
  for (int o = 32; o > 0; o >>= 1) m = fmaxf(m, __shfl_down(m, o));
  __shared__ float red[2];
  if (lane == 0) red[w] = m;
  __syncthreads();
  if (threadIdx.x == 0) {
    float tmax = fmaxf(red[0], red[1]);
    DECAY[base + j] = expf((-tmax) / 3.0f);
  }
}

// ---------------------------------------------------------------------------
// Kernel 6: keep -> stable compaction -> batched outputs.
// ---------------------------------------------------------------------------
__global__ void out_kernel(const float* __restrict__ boxes,
                           const float* __restrict__ CONF,
                           const int* __restrict__ LAB,
                           const float* __restrict__ DECAY,
                           float* __restrict__ out) {
  int b = blockIdx.x;
  int j = threadIdx.x;  // 0..1023
  int wave = j >> 6, lane = j & 63;
  int base = b * NBOX;
  float cf = CONF[base + j];
  float dc = DECAY[base + j];
  bool keep = (cf * dc) > KEEP_THR;

  unsigned long long mask = __ballot(keep);
  int wprefix = __popcll(mask & ((1ull << lane) - 1ull));
  __shared__ int wsum[16];
  __shared__ int wbase[16];
  __shared__ int s_total;
  if (lane == 0) wsum[wave] = __popcll(mask);
  __syncthreads();
  if (j == 0) {
    int acc = 0;
    for (int w = 0; w < 16; ++w) { wbase[w] = acc; acc += wsum[w]; }
    s_total = acc;
  }
  __syncthreads();
  int total = s_total;
  int num = min(total, MAXM);
  int pos = wbase[wave] + wprefix;

  float* o_num = out;
  float* o_box = out + BATCH;
  float* o_scr = out + BATCH + BATCH * MAXM * 5;
  float* o_cls = out + BATCH + BATCH * MAXM * 5 + BATCH * MAXM;

  if (j == 0) o_num[b] = (float)num;

  if (keep && pos < MAXM) {
    const float* src = boxes + (size_t)(base + j) * 5;
    float* dst = o_box + (size_t)(b * MAXM + pos) * 5;
#pragma unroll
    for (int k = 0; k < 5; ++k) dst[k] = src[k];
    o_scr[b * MAXM + pos] = cf;
    o_cls[b * MAXM + pos] = (float)LAB[base + j];
  }
  if (j >= num && j < MAXM) {
    float* dst = o_box + (size_t)(b * MAXM + j) * 5;
#pragma unroll
    for (int k = 0; k < 5; ++k) dst[k] = -1.0f;
    o_scr[b * MAXM + j] = -1.0f;
    o_cls[b * MAXM + j] = -1.0f;
  }
}

// ---------------------------------------------------------------------------
extern "C" void kernel_launch(void* const* d_in, const int* in_sizes, int n_in,
                              void* d_out, int out_size, void* d_ws, size_t ws_size,
                              hipStream_t stream) {
  const float* boxes = (const float*)d_in[0];   // [B, N, 5]
  const float* scores = (const float*)d_in[1];  // [B, N, C]
  float* out = (float*)d_out;

  char* w = (char*)d_ws;
  float4* G1   = (float4*)(w);                       // 524288
  float* VC    = (float*)(w + 524288);               // 131072
  float* DET   = (float*)(w + 655360);               // 131072
  float* CONF  = (float*)(w + 786432);               // 131072
  float* CMAX  = (float*)(w + 917504);               // 131072
  float* CI2   = (float*)(w + 1048576);              // 131072
  float* PREMIN= (float*)(w + 1179648);              // 131072 (32 used)
  float* DECAY = (float*)(w + 1310720);              // 131072
  int*   LAB   = (int*)  (w + 1441792);              // 131072
  unsigned short* NCNT = (unsigned short*)(w + 1572864);   // 131072
  unsigned short* NIDX = (unsigned short*)(w + 1703936);   // 33,521,664
  float* IOUC  = (float*)(w + 35225600);             // 67,043,328 (optional)
  const size_t need_iouc = 35225600 + (size_t)BATCH * TRI_PER_B * 4;
  const bool iouc_path = (ws_size >= need_iouc);

  const int BN = BATCH * NBOX;
  prep_kernel<<<(BN + 255) / 256, 256, 0, stream>>>(boxes, scores, G1, VC, DET,
                                                    CONF, LAB);
  certify_kernel<<<dim3(NBOX, BATCH), 128, 0, stream>>>(G1, VC, NIDX, NCNT);

  if (iouc_path) {
    cmax_kernel<true><<<dim3(NBOX, BATCH), 128, 0, stream>>>(G1, VC, DET, NIDX,
                                                             NCNT, CMAX, IOUC);
  } else {
    cmax_kernel<false><<<dim3(NBOX, BATCH), 128, 0, stream>>>(G1, VC, DET, NIDX,
                                                              NCNT, CMAX, IOUC);
  }

  minci2_kernel<<<BATCH, NBOX, 0, stream>>>(CMAX, CI2, PREMIN);

  if (iouc_path) {
    decay_kernel<true><<<dim3(NBOX, BATCH), 128, 0, stream>>>(
        G1, VC, DET, NIDX, NCNT, CI2, PREMIN, IOUC, DECAY);
  } else {
    decay_kernel<false><<<dim3(NBOX, BATCH), 128, 0, stream>>>(
        G1, VC, DET, NIDX, NCNT, CI2, PREMIN, IOUC, DECAY);
  }

  out_kernel<<<BATCH, 1024, 0, stream>>>(boxes, CONF, LAB, DECAY, out);
}

// Round 5
// 13.694 us; speedup vs baseline: 12.0195x; 5.5659x over previous
//
#include <hip/hip_runtime.h>

// Problem constants (match reference)
#define BATCH 32
#define NBOX 1024
#define NCLS 15
#define MAXM 300
#define CONF_THR 0.1f
#define KEEP_THR 0.2f
#define FEPS 1e-7f

// Sound decay bounds (f32): every decay-matrix element = exp(-(vv - ci2)/3)
// with vv = iou^2 in [0, 1.0f] (iou = 1 - sqrt(nonneg) <= 1.0f) and
// ci2 = cmax^2 in [0, 1.0f] (cmax has a 0 floor from the triu zeros).
//   => decay = min(elements) in [exp(-1/3)-ulp, exp(1/3)+ulp]
//           subset of [0.716530, 1.395613].
// conf >= C_HI: conf*decay >= 0.2794*0.716530 = 0.200199 > 0.2 -> keep.
// conf <= C_LO: conf*decay <= 0.1432*1.395613 = 0.199852 < 0.2 -> reject.
#define C_HI 0.2794f
#define C_LO 0.1432f

// ---------------------------------------------------------------------------
// Full reference ProbIoU chain (operand 1 = row i, operand 2 = column j),
// bit-exact op order, contraction off.
// ---------------------------------------------------------------------------
__device__ __forceinline__ float pair_iou(
    float x1, float y1, float a1, float b1, float c1, float det1,
    float x2, float y2, float a2, float b2, float c2, float det2) {
#pragma clang fp contract(off)
  float dx = x1 - x2;
  float dy = y1 - y2;
  float sa = a1 + a2;
  float sb = b1 + b2;
  float sc = c1 + c2;
  float denom = sa * sb - sc * sc + FEPS;
  float t1 = (sa * dy * dy + sb * dx * dx) / denom * 0.25f;
  float t2 = (sc * (-dx) * dy) / denom * 0.5f;
  float t3 = 0.5f * logf(denom / (4.0f * sqrtf(det1 * det2) + FEPS) + FEPS);
  float bd = t1 + t2 + t3;
  bd = fminf(fmaxf(bd, FEPS), 100.0f);
  float hd = sqrtf(1.0f - expf(-bd) + FEPS);
  return 1.0f - hd;
}

// ---------------------------------------------------------------------------
// Kernel 1: conf/label + keep classification.
//   KEEPD: 2 = keep guaranteed, 1 = ambiguous (needs decay), 0 = reject.
//   AMBP[block] = # ambiguous rows in this 256-row chunk (4 chunks/batch).
// ---------------------------------------------------------------------------
__global__ void prep_classify(const float* __restrict__ scores,
                              float* __restrict__ CONF, int* __restrict__ LAB,
                              unsigned char* __restrict__ KEEPD,
                              int* __restrict__ AMBP) {
#pragma clang fp contract(off)
  int idx = blockIdx.x * 256 + threadIdx.x;  // 128 blocks x 256 = B*N
  const float* sc = scores + (size_t)idx * NCLS;
  float best = sc[0];
  int lab = 0;
  for (int c = 1; c < NCLS; ++c) {
    float s = sc[c];
    if (s > best) { best = s; lab = c; }  // first-max = argmax semantics
  }
  float conf = (best < CONF_THR) ? 0.0f : best;
  CONF[idx] = conf;
  LAB[idx] = lab;
  unsigned char cls = (conf >= C_HI) ? 2 : ((conf > C_LO) ? 1 : 0);
  KEEPD[idx] = cls;

  unsigned long long mb = __ballot(cls == 1);
  __shared__ int ws[4];
  int wave = threadIdx.x >> 6, lane = threadIdx.x & 63;
  if (lane == 0) ws[wave] = __popcll(mb);
  __syncthreads();
  if (threadIdx.x == 0) AMBP[blockIdx.x] = ws[0] + ws[1] + ws[2] + ws[3];
}

// ---------------------------------------------------------------------------
// Kernel 2: fallback — only if this batch has ambiguous rows (never for the
// bench data). One 1024-thread block per batch; everything LDS-staged.
// Phase 1: cmax per row (bit-exact reference chain), ci2, premin.
// Phase 2: decay for each ambiguous row j:
//   tmax = max( max_{i<j}(iou^2 - ci2_i), -premin );  decay = exp(-tmax/3).
// ---------------------------------------------------------------------------
__global__ void fallback_kernel(const float* __restrict__ boxes,
                                const unsigned char* __restrict__ KEEPD,
                                const int* __restrict__ AMBP,
                                float* __restrict__ DECAY) {
#pragma clang fp contract(off)
  int b = blockIdx.x, t = threadIdx.x;
  int amb = AMBP[b * 4] + AMBP[b * 4 + 1] + AMBP[b * 4 + 2] + AMBP[b * 4 + 3];
  if (amb == 0) return;

  __shared__ float sX[NBOX], sY[NBOX], sA[NBOX], sB[NBOX], sC[NBOX], sD[NBOX];
  __shared__ float sCI2[NBOX];
  __shared__ float red[16];
  __shared__ float s_premin;

  const float* bx = boxes + ((size_t)(b * NBOX + t)) * 5;
  {
    float w = bx[2], h = bx[3], r = bx[4];
    float a = w * w / 12.0f;
    float bb = h * h / 12.0f;
    float cs = cosf(r), sn = sinf(r);
    float va = a * cs * cs + bb * sn * sn;
    float vb = a * sn * sn + bb * cs * cs;
    float vc = (a - bb) * cs * sn;
    sX[t] = bx[0];
    sY[t] = bx[1];
    sA[t] = va;
    sB[t] = vb;
    sC[t] = vc;
    sD[t] = fmaxf(va * vb - vc * vc, 0.0f);
  }
  __syncthreads();

  // Phase 1: cmax for row t = max(0, max_{i<t} iou(i, t))
  float m = 0.0f;
  for (int i = 0; i < t; ++i) {
    float v = pair_iou(sX[i], sY[i], sA[i], sB[i], sC[i], sD[i],
                       sX[t], sY[t], sA[t], sB[t], sC[t], sD[t]);
    m = fmaxf(m, v);
  }
  float c2 = m * m;
  sCI2[t] = c2;

  // premin = min over all rows of ci2
  float pm = c2;
  for (int o = 32; o > 0; o >>= 1) pm = fminf(pm, __shfl_down(pm, o));
  if ((t & 63) == 0) red[t >> 6] = pm;
  __syncthreads();
  if (t == 0) {
    float mm = red[0];
    for (int k = 1; k < 16; ++k) mm = fminf(mm, red[k]);
    s_premin = mm;
  }
  __syncthreads();

  // Phase 2: decay for ambiguous rows only
  for (int j = 0; j < NBOX; ++j) {
    if (KEEPD[b * NBOX + j] != 1) continue;  // uniform branch
    float mm = -s_premin;
    if (t < j) {
      float v = pair_iou(sX[t], sY[t], sA[t], sB[t], sC[t], sD[t],
                         sX[j], sY[j], sA[j], sB[j], sC[j], sD[j]);
      float vv = v * v;
      mm = fmaxf(mm, vv - sCI2[t]);
    }
    for (int o = 32; o > 0; o >>= 1) mm = fmaxf(mm, __shfl_down(mm, o));
    if ((t & 63) == 0) red[t >> 6] = mm;
    __syncthreads();
    if (t == 0) {
      float mx = red[0];
      for (int k = 1; k < 16; ++k) mx = fmaxf(mx, red[k]);
      DECAY[b * NBOX + j] = expf((-mx) / 3.0f);
    }
    __syncthreads();
  }
}

// ---------------------------------------------------------------------------
// Kernel 3: keep -> stable compaction -> batched outputs.
// ---------------------------------------------------------------------------
__global__ void out_kernel(const float* __restrict__ boxes,
                           const float* __restrict__ CONF,
                           const int* __restrict__ LAB,
                           const unsigned char* __restrict__ KEEPD,
                           const float* __restrict__ DECAY,
                           float* __restrict__ out) {
  int b = blockIdx.x;
  int j = threadIdx.x;  // 0..1023
  int wave = j >> 6, lane = j & 63;
  int base = b * NBOX;
  float cf = CONF[base + j];
  unsigned char kd = KEEPD[base + j];
  bool keep;
  if (kd == 2) keep = true;
  else if (kd == 0) keep = false;
  else keep = (cf * DECAY[base + j]) > KEEP_THR;

  unsigned long long mask = __ballot(keep);
  int wprefix = __popcll(mask & ((1ull << lane) - 1ull));
  __shared__ int wsum[16];
  __shared__ int wbase[16];
  __shared__ int s_total;
  if (lane == 0) wsum[wave] = __popcll(mask);
  __syncthreads();
  if (j == 0) {
    int acc = 0;
    for (int w = 0; w < 16; ++w) { wbase[w] = acc; acc += wsum[w]; }
    s_total = acc;
  }
  __syncthreads();
  int total = s_total;
  int num = min(total, MAXM);
  int pos = wbase[wave] + wprefix;

  float* o_num = out;
  float* o_box = out + BATCH;
  float* o_scr = out + BATCH + BATCH * MAXM * 5;
  float* o_cls = out + BATCH + BATCH * MAXM * 5 + BATCH * MAXM;

  if (j == 0) o_num[b] = (float)num;

  if (keep && pos < MAXM) {
    const float* src = boxes + (size_t)(base + j) * 5;
    float* dst = o_box + (size_t)(b * MAXM + pos) * 5;
#pragma unroll
    for (int k = 0; k < 5; ++k) dst[k] = src[k];
    o_scr[b * MAXM + pos] = cf;
    o_cls[b * MAXM + pos] = (float)LAB[base + j];
  }
  if (j >= num && j < MAXM) {
    float* dst = o_box + (size_t)(b * MAXM + j) * 5;
#pragma unroll
    for (int k = 0; k < 5; ++k) dst[k] = -1.0f;
    o_scr[b * MAXM + j] = -1.0f;
    o_cls[b * MAXM + j] = -1.0f;
  }
}

// ---------------------------------------------------------------------------
extern "C" void kernel_launch(void* const* d_in, const int* in_sizes, int n_in,
                              void* d_out, int out_size, void* d_ws, size_t ws_size,
                              hipStream_t stream) {
  const float* boxes = (const float*)d_in[0];   // [B, N, 5]
  const float* scores = (const float*)d_in[1];  // [B, N, C]
  float* out = (float*)d_out;

  char* w = (char*)d_ws;
  float* CONF  = (float*)(w);                          // 131072 B
  int*   LAB   = (int*)  (w + 131072);                 // 131072 B
  float* DECAY = (float*)(w + 262144);                 // 131072 B
  unsigned char* KEEPD = (unsigned char*)(w + 393216); //  32768 B
  int*   AMBP  = (int*)  (w + 425984);                 //    512 B

  prep_classify<<<(BATCH * NBOX) / 256, 256, 0, stream>>>(scores, CONF, LAB,
                                                          KEEPD, AMBP);
  fallback_kernel<<<BATCH, NBOX, 0, stream>>>(boxes, KEEPD, AMBP, DECAY);
  out_kernel<<<BATCH, NBOX, 0, stream>>>(boxes, CONF, LAB, KEEPD, DECAY, out);
}

// Round 6
// 9.412 us; speedup vs baseline: 17.4880x; 1.4550x over previous
//
#include <hip/hip_runtime.h>

// Problem constants (match reference)
#define BATCH 32
#define NBOX 1024
#define NCLS 15
#define MAXM 300
#define CONF_THR 0.1f
#define KEEP_THR 0.2f
#define FEPS 1e-7f

// Sound decay bounds (f32): every decay-matrix element = exp(-(vv - ci2)/3)
// with vv = iou^2 in [0, 1.0f] (iou = 1 - sqrt(nonneg) <= 1.0f) and
// ci2 = cmax^2 in [0, 1.0f] (cmax has a 0 floor from the triu zeros).
//   => decay = min(elements) in [exp(-1/3)-ulp, exp(1/3)+ulp]
//           subset of [0.716530, 1.395613].
// conf >= C_HI: conf*decay >= 0.2794*0.716530 = 0.200199 > 0.2 -> keep.
// conf <= C_LO: conf*decay <= 0.1432*1.395613 = 0.199852 < 0.2 -> reject.
#define C_HI 0.2794f
#define C_LO 0.1432f

// ---------------------------------------------------------------------------
// Full reference ProbIoU chain (operand 1 = row i, operand 2 = column j),
// bit-exact op order, contraction off.
// ---------------------------------------------------------------------------
__device__ __forceinline__ float pair_iou(
    float x1, float y1, float a1, float b1, float c1, float det1,
    float x2, float y2, float a2, float b2, float c2, float det2) {
#pragma clang fp contract(off)
  float dx = x1 - x2;
  float dy = y1 - y2;
  float sa = a1 + a2;
  float sb = b1 + b2;
  float sc = c1 + c2;
  float denom = sa * sb - sc * sc + FEPS;
  float t1 = (sa * dy * dy + sb * dx * dx) / denom * 0.25f;
  float t2 = (sc * (-dx) * dy) / denom * 0.5f;
  float t3 = 0.5f * logf(denom / (4.0f * sqrtf(det1 * det2) + FEPS) + FEPS);
  float bd = t1 + t2 + t3;
  bd = fminf(fmaxf(bd, FEPS), 100.0f);
  float hd = sqrtf(1.0f - expf(-bd) + FEPS);
  return 1.0f - hd;
}

// ---------------------------------------------------------------------------
// Single fused kernel: one block per batch, 1024 threads (thread = row j).
//   1) conf/label/class from the 15 class scores.
//   2) ballot-count ambiguous rows (conf in (C_LO, C_HI)).
//   3) IF any ambiguous (never on bench data): LDS-staged bit-exact Matrix-NMS
//      to get decay for the ambiguous rows only.
//   4) keep decision -> stable ballot prefix-scan compaction -> outputs.
// No workspace use at all.
// ---------------------------------------------------------------------------
__global__ void __launch_bounds__(NBOX)
fused_kernel(const float* __restrict__ boxes,
             const float* __restrict__ scores,
             float* __restrict__ out) {
#pragma clang fp contract(off)
  const int b = blockIdx.x;
  const int j = threadIdx.x;  // 0..1023
  const int wave = j >> 6, lane = j & 63;
  const int base = b * NBOX;

  // ---- 1) conf / label ----
  const float* sc = scores + (size_t)(base + j) * NCLS;
  float best = sc[0];
  int lab = 0;
#pragma unroll
  for (int c = 1; c < NCLS; ++c) {
    float s = sc[c];
    if (s > best) { best = s; lab = c; }  // first-max = argmax semantics
  }
  float conf = (best < CONF_THR) ? 0.0f : best;
  int cls = (conf >= C_HI) ? 2 : ((conf > C_LO) ? 1 : 0);

  // ---- 2) ambiguous count ----
  __shared__ int s_ambw[16];
  __shared__ int s_amb;
  unsigned long long ambmask = __ballot(cls == 1);
  if (lane == 0) s_ambw[wave] = __popcll(ambmask);
  __syncthreads();
  if (j == 0) {
    int acc = 0;
#pragma unroll
    for (int w = 0; w < 16; ++w) acc += s_ambw[w];
    s_amb = acc;
  }
  __syncthreads();

  // ---- 3) rare exact fallback (bit-exact reference chain) ----
  __shared__ float s_dec[NBOX];
  if (s_amb > 0) {
    __shared__ float sX[NBOX], sY[NBOX], sA[NBOX], sB[NBOX], sC[NBOX], sD[NBOX];
    __shared__ float sCI2[NBOX];
    __shared__ float red[16];
    __shared__ float s_premin;
    __shared__ unsigned long long s_ambm[16];
    if (lane == 0) s_ambm[wave] = ambmask;

    const float* bx = boxes + (size_t)(base + j) * 5;
    {
      float w = bx[2], h = bx[3], r = bx[4];
      float a = w * w / 12.0f;
      float bb = h * h / 12.0f;
      float cs = cosf(r), sn = sinf(r);
      float va = a * cs * cs + bb * sn * sn;
      float vb = a * sn * sn + bb * cs * cs;
      float vc = (a - bb) * cs * sn;
      sX[j] = bx[0];
      sY[j] = bx[1];
      sA[j] = va;
      sB[j] = vb;
      sC[j] = vc;
      sD[j] = fmaxf(va * vb - vc * vc, 0.0f);
    }
    __syncthreads();

    // cmax for column j = max(0, max_{i<j} iou(i, j)); ci2 = cmax^2
    float m = 0.0f;
    for (int i = 0; i < j; ++i) {
      float v = pair_iou(sX[i], sY[i], sA[i], sB[i], sC[i], sD[i],
                         sX[j], sY[j], sA[j], sB[j], sC[j], sD[j]);
      m = fmaxf(m, v);
    }
    float c2 = m * m;
    sCI2[j] = c2;

    // premin = min_i ci2 (covers all far / i>=j candidates: -ci2_i <= vv-ci2_i)
    float pm = c2;
    for (int o = 32; o > 0; o >>= 1) pm = fminf(pm, __shfl_down(pm, o));
    if (lane == 0) red[wave] = pm;
    __syncthreads();
    if (j == 0) {
      float mm = red[0];
#pragma unroll
      for (int k = 1; k < 16; ++k) mm = fminf(mm, red[k]);
      s_premin = mm;
    }
    __syncthreads();

    // decay for each ambiguous column jj (block-uniform loop over set bits)
    for (int w = 0; w < 16; ++w) {
      unsigned long long wm = s_ambm[w];
      while (wm) {
        int jj = (w << 6) + __ffsll((long long)wm) - 1;
        wm &= wm - 1;
        float mm = -s_premin;
        if (j < jj) {
          float v = pair_iou(sX[j], sY[j], sA[j], sB[j], sC[j], sD[j],
                             sX[jj], sY[jj], sA[jj], sB[jj], sC[jj], sD[jj]);
          float vv = v * v;
          mm = fmaxf(mm, vv - sCI2[j]);
        }
        for (int o = 32; o > 0; o >>= 1) mm = fmaxf(mm, __shfl_down(mm, o));
        if (lane == 0) red[wave] = mm;
        __syncthreads();
        if (j == 0) {
          float mx = red[0];
#pragma unroll
          for (int k = 1; k < 16; ++k) mx = fmaxf(mx, red[k]);
          s_dec[jj] = expf((-mx) / 3.0f);
        }
        __syncthreads();
      }
    }
  }

  // ---- 4) keep -> stable compaction -> outputs ----
  bool keep;
  if (cls == 2) keep = true;
  else if (cls == 0) keep = false;
  else keep = (conf * s_dec[j]) > KEEP_THR;

  unsigned long long mask = __ballot(keep);
  int wprefix = __popcll(mask & ((1ull << lane) - 1ull));
  __shared__ int wsum[16];
  __shared__ int wbase[16];
  __shared__ int s_total;
  if (lane == 0) wsum[wave] = __popcll(mask);
  __syncthreads();
  if (j == 0) {
    int acc = 0;
#pragma unroll
    for (int w = 0; w < 16; ++w) { wbase[w] = acc; acc += wsum[w]; }
    s_total = acc;
  }
  __syncthreads();
  int num = min(s_total, MAXM);
  int pos = wbase[wave] + wprefix;

  float* o_num = out;
  float* o_box = out + BATCH;
  float* o_scr = out + BATCH + BATCH * MAXM * 5;
  float* o_cls = out + BATCH + BATCH * MAXM * 5 + BATCH * MAXM;

  if (j == 0) o_num[b] = (float)num;

  if (keep && pos < MAXM) {
    const float* src = boxes + (size_t)(base + j) * 5;
    float* dst = o_box + (size_t)(b * MAXM + pos) * 5;
#pragma unroll
    for (int k = 0; k < 5; ++k) dst[k] = src[k];
    o_scr[b * MAXM + pos] = conf;
    o_cls[b * MAXM + pos] = (float)lab;
  }
  if (j >= num && j < MAXM) {
    float* dst = o_box + (size_t)(b * MAXM + j) * 5;
#pragma unroll
    for (int k = 0; k < 5; ++k) dst[k] = -1.0f;
    o_scr[b * MAXM + j] = -1.0f;
    o_cls[b * MAXM + j] = -1.0f;
  }
}

// ---------------------------------------------------------------------------
extern "C" void kernel_launch(void* const* d_in, const int* in_sizes, int n_in,
                              void* d_out, int out_size, void* d_ws, size_t ws_size,
                              hipStream_t stream) {
  const float* boxes = (const float*)d_in[0];   // [B, N, 5]
  const float* scores = (const float*)d_in[1];  // [B, N, C]
  float* out = (float*)d_out;
  fused_kernel<<<BATCH, NBOX, 0, stream>>>(boxes, scores, out);
}